// Round 1
// baseline (123.490 us; speedup 1.0000x reference)
//
#include <hip/hip_runtime.h>

// Chamfer distance, brute force, fp32 VALU.
// dist(p,q) = |p|^2 + |q|^2 - 2 p.q ; |p|^2 folded out of the min (constant
// per thread), |q|^2 precomputed during LDS staging -> 3 FMA + 1 min per pair.
//
// Block = 256 threads = 128 points x 2 target-halves (half uniform per wave,
// so inner-loop LDS reads are wave-uniform broadcasts -> no bank conflicts).
// Grid = B * 2 directions * (M/128) = 512 blocks -> 2 blocks/CU, 2 waves/SIMD.

#define THREADS 256
#define HALF_PTS 128
#define TILE 1024  // targets per half per staging tile (2*TILE*16B = 32 KB LDS)

__global__ __launch_bounds__(THREADS) void chamfer_min_kernel(
    const float* __restrict__ pred, const float* __restrict__ target,
    float* __restrict__ partial, int M) {
  const int blocksPerDir = M / HALF_PTS;  // 64
  int pblk = blockIdx.x % blocksPerDir;
  int bd = blockIdx.x / blocksPerDir;
  int dir = bd & 1;
  int b = bd >> 1;
  const float* src = (dir ? target : pred) + (size_t)b * M * 3;
  const float* ref = (dir ? pred : target) + (size_t)b * M * 3;

  __shared__ float4 lds[2 * TILE];
  __shared__ float halfmin[HALF_PTS];
  __shared__ float wsum[2];

  int tid = threadIdx.x;
  int pt = pblk * HALF_PTS + (tid & (HALF_PTS - 1));
  int half = tid >> 7;  // 0 for waves 0-1, 1 for waves 2-3

  float px = src[pt * 3 + 0];
  float py = src[pt * 3 + 1];
  float pz = src[pt * 3 + 2];
  float cm = px * px + py * py + pz * pz;
  float ax = -2.0f * px, ay = -2.0f * py, az = -2.0f * pz;

  float m0 = 3.0e38f, m1 = 3.0e38f;

  const int halfN = M >> 1;        // 4096 targets per half
  const int ntiles = halfN / TILE; // 4
  for (int k = 0; k < ntiles; ++k) {
    __syncthreads();  // previous tile's readers done before overwrite
    // Stage tile k for both halves: float4{qx,qy,qz,|q|^2}
    for (int j = tid; j < 2 * TILE; j += THREADS) {
      int h = j >> 10;          // j / TILE
      int jj = j & (TILE - 1);  // j % TILE
      int n = h * halfN + k * TILE + jj;
      float qx = ref[n * 3 + 0];
      float qy = ref[n * 3 + 1];
      float qz = ref[n * 3 + 2];
      lds[j] = make_float4(qx, qy, qz, qx * qx + qy * qy + qz * qz);
    }
    __syncthreads();
    const float4* tp = lds + half * TILE;  // wave-uniform base
    #pragma unroll 4
    for (int j = 0; j < TILE; j += 4) {
      float4 q0 = tp[j + 0];  // uniform address -> broadcast, conflict-free
      float4 q1 = tp[j + 1];
      float4 q2 = tp[j + 2];
      float4 q3 = tp[j + 3];
      float d0 = fmaf(ax, q0.x, fmaf(ay, q0.y, fmaf(az, q0.z, q0.w)));
      float d1 = fmaf(ax, q1.x, fmaf(ay, q1.y, fmaf(az, q1.z, q1.w)));
      float d2 = fmaf(ax, q2.x, fmaf(ay, q2.y, fmaf(az, q2.z, q2.w)));
      float d3 = fmaf(ax, q3.x, fmaf(ay, q3.y, fmaf(az, q3.z, q3.w)));
      m0 = fminf(fminf(m0, d0), d1);  // v_min3 fusion
      m1 = fminf(fminf(m1, d2), d3);
    }
  }
  float myMin = cm + fminf(m0, m1);

  // Combine the two target-halves per point, then sum the 128 point-mins.
  __syncthreads();
  if (half == 1) halfmin[tid & (HALF_PTS - 1)] = myMin;
  __syncthreads();
  float v = 0.0f;
  if (half == 0) v = fminf(myMin, halfmin[tid]);
  // Waves 0 and 1 hold the 128 combined mins; shuffle sum-reduce width 64.
  for (int off = 32; off > 0; off >>= 1) v += __shfl_down(v, off, 64);
  if (tid < HALF_PTS && (tid & 63) == 0) wsum[tid >> 6] = v;
  __syncthreads();
  if (tid == 0) partial[blockIdx.x] = wsum[0] + wsum[1];
}

__global__ __launch_bounds__(256) void chamfer_reduce_kernel(
    const float* __restrict__ partial, float* __restrict__ out, int n,
    float scale) {
  float s = 0.0f;
  for (int i = threadIdx.x; i < n; i += 256) s += partial[i];
  for (int off = 32; off > 0; off >>= 1) s += __shfl_down(s, off, 64);
  __shared__ float ws[4];
  if ((threadIdx.x & 63) == 0) ws[threadIdx.x >> 6] = s;
  __syncthreads();
  if (threadIdx.x == 0) out[0] = (ws[0] + ws[1] + ws[2] + ws[3]) * scale;
}

extern "C" void kernel_launch(void* const* d_in, const int* in_sizes, int n_in,
                              void* d_out, int out_size, void* d_ws,
                              size_t ws_size, hipStream_t stream) {
  const float* pred = (const float*)d_in[0];
  const float* target = (const float*)d_in[1];
  float* out = (float*)d_out;
  const int B = 4;
  const int M = in_sizes[0] / (B * 3);  // 8192
  float* partial = (float*)d_ws;        // B*2*(M/128) = 512 floats

  int blocks = B * 2 * (M / HALF_PTS);  // 512
  chamfer_min_kernel<<<blocks, THREADS, 0, stream>>>(pred, target, partial, M);

  // mean_b[ mean_m(min) + mean_n(min) ] with M==N  ->  sum_all / (B*M)
  float scale = 1.0f / (float)(B * M);
  chamfer_reduce_kernel<<<1, 256, 0, stream>>>(partial, out, blocks, scale);
}

// Round 2
// 102.868 us; speedup vs baseline: 1.2005x; 1.2005x over previous
//
#include <hip/hip_runtime.h>

// Chamfer distance, fp32 VALU, register-tiled.
// dist(p,q) = |p|^2 + |q|^2 - 2 p.q ; |p|^2 folded out of the min, |q|^2
// precomputed during LDS staging -> 3 FMA + 1 min per pair.
//
// R1 change: P=4 src points per thread amortizes each LDS broadcast read over
// 4 points (R0 was LDS-pipe-bound: 8.4M ds_read_b128 x 5.85cyc == the 80us).
// S=8 target slices per block keep grid at 512 blocks (8 waves/CU). A wave
// spans 2 slices -> 2 distinct broadcast addrs per ds_read (free, m136).
// Reduction fused: memsetAsync(out,0) + one atomicAdd per block.

#define THREADS 256
#define P 4      // src points per thread
#define S 8      // target slices per block (one 32-lane group per slice)
#define G 128    // src points per block = (THREADS/S)*P
#define TILE 256 // targets per slice per staging tile (S*TILE*16B = 32 KB LDS)

__global__ __launch_bounds__(THREADS) void chamfer_min_kernel(
    const float* __restrict__ pred, const float* __restrict__ target,
    float* __restrict__ out, int M, float scale) {
  const int blocksPerDir = M / G;  // 64
  int pblk = blockIdx.x % blocksPerDir;
  int bd = blockIdx.x / blocksPerDir;
  int dir = bd & 1;
  int b = bd >> 1;
  const float* src = (dir ? target : pred) + (size_t)b * M * 3;
  const float* ref = (dir ? pred : target) + (size_t)b * M * 3;

  __shared__ float4 lds[S * TILE];  // 32 KB; reused for the combine epilogue

  int t = threadIdx.x;
  int g = t >> 5;  // slice 0..7 (uniform per 32-lane group)
  int l = t & 31;

  float cm[P], ax[P], ay[P], az[P];
  int pbase = pblk * G;
#pragma unroll
  for (int j = 0; j < P; ++j) {
    int pt = pbase + l + 32 * j;
    float x = src[pt * 3 + 0], y = src[pt * 3 + 1], z = src[pt * 3 + 2];
    cm[j] = x * x + y * y + z * z;
    ax[j] = -2.f * x;
    ay[j] = -2.f * y;
    az[j] = -2.f * z;
  }
  float mins[P];
#pragma unroll
  for (int j = 0; j < P; ++j) mins[j] = 3.0e38f;

  const int sliceLen = M / S;          // 1024
  const int ntiles = sliceLen / TILE;  // 4
  for (int k = 0; k < ntiles; ++k) {
    __syncthreads();  // previous tile's readers done before overwrite
#pragma unroll
    for (int i = 0; i < (S * TILE) / THREADS; ++i) {  // 8 entries/thread
      int idx = t + THREADS * i;
      int s = idx / TILE;
      int jj = idx & (TILE - 1);
      int n = s * sliceLen + k * TILE + jj;
      float qx = ref[n * 3 + 0], qy = ref[n * 3 + 1], qz = ref[n * 3 + 2];
      lds[idx] = make_float4(qx, qy, qz, qx * qx + qy * qy + qz * qz);
    }
    __syncthreads();
    const float4* tp = lds + g * TILE;  // uniform per 32-lane group
    for (int j = 0; j < TILE; j += 4) {
      float4 q0 = tp[j + 0];  // broadcast reads, conflict-free
      float4 q1 = tp[j + 1];
      float4 q2 = tp[j + 2];
      float4 q3 = tp[j + 3];
#pragma unroll
      for (int p = 0; p < P; ++p) {
        float d0 = fmaf(ax[p], q0.x, fmaf(ay[p], q0.y, fmaf(az[p], q0.z, q0.w)));
        float d1 = fmaf(ax[p], q1.x, fmaf(ay[p], q1.y, fmaf(az[p], q1.z, q1.w)));
        float d2 = fmaf(ax[p], q2.x, fmaf(ay[p], q2.y, fmaf(az[p], q2.z, q2.w)));
        float d3 = fmaf(ax[p], q3.x, fmaf(ay[p], q3.y, fmaf(az[p], q3.z, q3.w)));
        mins[p] = fminf(fminf(mins[p], d0), d1);  // v_min3
        mins[p] = fminf(fminf(mins[p], d2), d3);
      }
    }
  }

  // Combine the S slice-mins per point, then sum the G point-mins.
  __syncthreads();
  float* lmin = (float*)lds;          // [S][G] floats (4 KB, overlays staging)
  float* lcm = (float*)lds + S * G;   // [G] floats
#pragma unroll
  for (int j = 0; j < P; ++j) {
    lmin[g * G + (l + 32 * j)] = mins[j];
    if (g == 0) lcm[l + 32 * j] = cm[j];  // cm identical across slices
  }
  __syncthreads();
  float v = 0.f;
  if (t < G) {
    float mn = 3.0e38f;
#pragma unroll
    for (int s = 0; s < S; ++s) mn = fminf(mn, lmin[s * G + t]);  // no conflicts
    v = lcm[t] + mn;
  }
  for (int off = 32; off > 0; off >>= 1) v += __shfl_down(v, off, 64);
  __shared__ float ws[THREADS / 64];
  if ((t & 63) == 0) ws[t >> 6] = v;
  __syncthreads();
  if (t == 0) {
    float bsum = 0.f;
#pragma unroll
    for (int w = 0; w < THREADS / 64; ++w) bsum += ws[w];
    atomicAdd(out, bsum * scale);
  }
}

extern "C" void kernel_launch(void* const* d_in, const int* in_sizes, int n_in,
                              void* d_out, int out_size, void* d_ws,
                              size_t ws_size, hipStream_t stream) {
  const float* pred = (const float*)d_in[0];
  const float* target = (const float*)d_in[1];
  float* out = (float*)d_out;
  const int B = 4;
  const int M = in_sizes[0] / (B * 3);  // 8192

  // mean_b[ mean_m(min) + mean_n(min) ] with M==N  ->  sum_all / (B*M)
  float scale = 1.0f / (float)(B * M);

  hipMemsetAsync(out, 0, sizeof(float), stream);  // d_out is poisoned 0xAA
  int blocks = B * 2 * (M / G);                   // 512
  chamfer_min_kernel<<<blocks, THREADS, 0, stream>>>(pred, target, out, M,
                                                     scale);
}

// Round 3
// 97.131 us; speedup vs baseline: 1.2714x; 1.0591x over previous
//
#include <hip/hip_runtime.h>

// Chamfer distance, fp32 VALU, register-tiled.
// dist(p,q) = |p|^2 + |q|^2 - 2 p.q ; |p|^2 folded out of the min, |q|^2
// precomputed during LDS staging -> 3 FMA + 0.5 v_min3 per pair.
//
// R2 post-mortem: VALUBusy=90% was the gfx94x formula (4cyc/instr); true VALU
// is ~43% of runtime. LDS pipe (8192 b128/CU x ~5.8cyc) + lgkmcnt stalls at
// 2 waves/SIMD are the real limiter.
// R3: P=8 pts/thread, S=16 slices (16-lane groups) halves LDS reads at equal
// VALU and equal grid (512 blocks, 8 waves/CU). Slice pad +1 float4 puts the
// wave's 4 distinct broadcast addrs on disjoint banks (stride 2064B -> bank
// offset 4/group). unroll 2 keeps 8 ds_reads in flight.

#define THREADS 256
#define P 8        // src points per thread
#define S 16       // target slices per block (one 16-lane group per slice)
#define G 128      // src points per block = (THREADS/S)*P
#define TILE 128   // targets per slice per staging tile
#define LSTRIDE (TILE + 1)  // +1 float4 pad -> disjoint banks across groups

__global__ __launch_bounds__(THREADS) void chamfer_min_kernel(
    const float* __restrict__ pred, const float* __restrict__ target,
    float* __restrict__ out, int M, float scale) {
  const int blocksPerDir = M / G;  // 64
  int pblk = blockIdx.x % blocksPerDir;
  int bd = blockIdx.x / blocksPerDir;
  int dir = bd & 1;
  int b = bd >> 1;
  const float* src = (dir ? target : pred) + (size_t)b * M * 3;
  const float* ref = (dir ? pred : target) + (size_t)b * M * 3;

  __shared__ float4 lds[S * LSTRIDE];  // ~33 KB; reused for combine epilogue

  int t = threadIdx.x;
  int g = t >> 4;  // slice 0..15 (uniform per 16-lane group)
  int l = t & 15;

  float cm[P], ax[P], ay[P], az[P];
  int pbase = pblk * G;
#pragma unroll
  for (int j = 0; j < P; ++j) {
    int pt = pbase + l + 16 * j;
    float x = src[pt * 3 + 0], y = src[pt * 3 + 1], z = src[pt * 3 + 2];
    cm[j] = x * x + y * y + z * z;
    ax[j] = -2.f * x;
    ay[j] = -2.f * y;
    az[j] = -2.f * z;
  }
  float mins[P];
#pragma unroll
  for (int j = 0; j < P; ++j) mins[j] = 3.0e38f;

  const int sliceLen = M / S;          // 512
  const int ntiles = sliceLen / TILE;  // 4
  for (int k = 0; k < ntiles; ++k) {
    __syncthreads();  // previous tile's readers done before overwrite
#pragma unroll
    for (int i = 0; i < (S * TILE) / THREADS; ++i) {  // 8 entries/thread
      int idx = t + THREADS * i;
      int s = idx >> 7;         // idx / TILE
      int jj = idx & (TILE - 1);
      int n = s * sliceLen + k * TILE + jj;
      float qx = ref[n * 3 + 0], qy = ref[n * 3 + 1], qz = ref[n * 3 + 2];
      lds[s * LSTRIDE + jj] = make_float4(qx, qy, qz, qx * qx + qy * qy + qz * qz);
    }
    __syncthreads();
    const float4* tp = lds + g * LSTRIDE;  // uniform per 16-lane group
#pragma unroll 2
    for (int j = 0; j < TILE; j += 4) {
      float4 q0 = tp[j + 0];  // broadcast reads, disjoint banks across groups
      float4 q1 = tp[j + 1];
      float4 q2 = tp[j + 2];
      float4 q3 = tp[j + 3];
#pragma unroll
      for (int p = 0; p < P; ++p) {
        float d0 = fmaf(ax[p], q0.x, fmaf(ay[p], q0.y, fmaf(az[p], q0.z, q0.w)));
        float d1 = fmaf(ax[p], q1.x, fmaf(ay[p], q1.y, fmaf(az[p], q1.z, q1.w)));
        float d2 = fmaf(ax[p], q2.x, fmaf(ay[p], q2.y, fmaf(az[p], q2.z, q2.w)));
        float d3 = fmaf(ax[p], q3.x, fmaf(ay[p], q3.y, fmaf(az[p], q3.z, q3.w)));
        mins[p] = fminf(fminf(mins[p], d0), d1);  // v_min3
        mins[p] = fminf(fminf(mins[p], d2), d3);
      }
    }
  }

  // Combine the S slice-mins per point, then sum the G point-mins.
  __syncthreads();
  float* lmin = (float*)lds;          // [S][G] floats (8 KB, overlays staging)
  float* lcm = (float*)lds + S * G;   // [G] floats
#pragma unroll
  for (int j = 0; j < P; ++j) {
    lmin[g * G + (l + 16 * j)] = mins[j];
    if (g == 0) lcm[l + 16 * j] = cm[j];  // cm identical across slices
  }
  __syncthreads();
  float v = 0.f;
  if (t < G) {
    float mn = 3.0e38f;
#pragma unroll
    for (int s = 0; s < S; ++s) mn = fminf(mn, lmin[s * G + t]);
    v = lcm[t] + mn;
  }
  for (int off = 32; off > 0; off >>= 1) v += __shfl_down(v, off, 64);
  __shared__ float ws[THREADS / 64];
  if ((t & 63) == 0) ws[t >> 6] = v;
  __syncthreads();
  if (t == 0) {
    float bsum = 0.f;
#pragma unroll
    for (int w = 0; w < THREADS / 64; ++w) bsum += ws[w];
    atomicAdd(out, bsum * scale);
  }
}

extern "C" void kernel_launch(void* const* d_in, const int* in_sizes, int n_in,
                              void* d_out, int out_size, void* d_ws,
                              size_t ws_size, hipStream_t stream) {
  const float* pred = (const float*)d_in[0];
  const float* target = (const float*)d_in[1];
  float* out = (float*)d_out;
  const int B = 4;
  const int M = in_sizes[0] / (B * 3);  // 8192

  // mean_b[ mean_m(min) + mean_n(min) ] with M==N  ->  sum_all / (B*M)
  float scale = 1.0f / (float)(B * M);

  hipMemsetAsync(out, 0, sizeof(float), stream);  // d_out is poisoned 0xAA
  int blocks = B * 2 * (M / G);                   // 512
  chamfer_min_kernel<<<blocks, THREADS, 0, stream>>>(pred, target, out, M,
                                                     scale);
}

// Round 4
// 96.880 us; speedup vs baseline: 1.2747x; 1.0026x over previous
//
#include <hip/hip_runtime.h>

// Chamfer distance, fp32 VALU, register-tiled, packed-fp32 math.
// dist(p,q) = |p|^2 + |q|^2 - 2 p.q ; |p|^2 folded out of the min, |q|^2
// precomputed during LDS staging.
//
// R3 post-mortem: broadcast ds_read_b128 is issue-bound (~4cyc, not 12) ->
// LDS pipe fine; true VALU = 47% of runtime (reported 95% = gfx94x formula
// x2); rest is latency at 2 waves/SIMD.
// R4: (a) v_pk_fma_f32 via inline asm (op_sel broadcasts the q component to
// both halves) -> 2 points per packed FMA chain, 3.5 -> 2.0 VALU ops/pair.
// (b) 512-thread blocks, S=32 slices of 16 lanes -> 512 blocks x 8 waves =
// 4 waves/SIMD (2x latency hiding). LDS 33.3KB -> 2 blocks/CU.

#define THREADS 512
#define P 8        // src points per thread (4 packed pairs)
#define S 32       // target slices per block (one 16-lane group per slice)
#define G 128      // src points per block = 16 lanes * P
#define TILE 64    // targets per slice per staging tile
#define LSTRIDE (TILE + 1)  // +1 float4 pad -> disjoint banks across groups

typedef float float2_t __attribute__((ext_vector_type(2)));
typedef float float4_t __attribute__((ext_vector_type(4)));

// d = a * bcast_lo(b) + bcast_hi(b)   (b = {qz,qw}: d = a*qz + qw)
static __device__ __forceinline__ float2_t pk_fma_bl_bh(float2_t a, float2_t b) {
  float2_t d;
  asm("v_pk_fma_f32 %0, %1, %2, %2 op_sel:[0,0,1] op_sel_hi:[1,0,1]"
      : "=v"(d) : "v"(a), "v"(b));
  return d;
}
// d = a * bcast_hi(b) + c
static __device__ __forceinline__ float2_t pk_fma_bh(float2_t a, float2_t b, float2_t c) {
  float2_t d;
  asm("v_pk_fma_f32 %0, %1, %2, %3 op_sel:[0,1,0] op_sel_hi:[1,1,1]"
      : "=v"(d) : "v"(a), "v"(b), "v"(c));
  return d;
}
// d = a * bcast_lo(b) + c
static __device__ __forceinline__ float2_t pk_fma_bl(float2_t a, float2_t b, float2_t c) {
  float2_t d;
  asm("v_pk_fma_f32 %0, %1, %2, %3 op_sel:[0,0,0] op_sel_hi:[1,0,1]"
      : "=v"(d) : "v"(a), "v"(b), "v"(c));
  return d;
}

__global__ __launch_bounds__(THREADS, 4) void chamfer_min_kernel(
    const float* __restrict__ pred, const float* __restrict__ target,
    float* __restrict__ out, int M, float scale) {
  const int blocksPerDir = M / G;  // 64
  int pblk = blockIdx.x % blocksPerDir;
  int bd = blockIdx.x / blocksPerDir;
  int dir = bd & 1;
  int b = bd >> 1;
  const float* src = (dir ? target : pred) + (size_t)b * M * 3;
  const float* ref = (dir ? pred : target) + (size_t)b * M * 3;

  __shared__ float4_t lds[S * LSTRIDE];  // 33.3 KB; reused in epilogue

  int t = threadIdx.x;
  int g = t >> 4;  // slice 0..31 (uniform per 16-lane group)
  int l = t & 15;

  float cm[P];
  float2_t a2x[P / 2], a2y[P / 2], a2z[P / 2];
  int pbase = pblk * G;
#pragma unroll
  for (int i = 0; i < P / 2; ++i) {
    int p0 = pbase + l + 16 * (2 * i);
    int p1 = pbase + l + 16 * (2 * i + 1);
    float x0 = src[p0 * 3 + 0], y0 = src[p0 * 3 + 1], z0 = src[p0 * 3 + 2];
    float x1 = src[p1 * 3 + 0], y1 = src[p1 * 3 + 1], z1 = src[p1 * 3 + 2];
    cm[2 * i] = x0 * x0 + y0 * y0 + z0 * z0;
    cm[2 * i + 1] = x1 * x1 + y1 * y1 + z1 * z1;
    a2x[i] = (float2_t){-2.f * x0, -2.f * x1};
    a2y[i] = (float2_t){-2.f * y0, -2.f * y1};
    a2z[i] = (float2_t){-2.f * z0, -2.f * z1};
  }
  float mlo[P / 2], mhi[P / 2];
#pragma unroll
  for (int i = 0; i < P / 2; ++i) { mlo[i] = 3.0e38f; mhi[i] = 3.0e38f; }

  const int sliceLen = M / S;          // 256
  const int ntiles = sliceLen / TILE;  // 4
  for (int k = 0; k < ntiles; ++k) {
    __syncthreads();  // previous tile's readers done before overwrite
#pragma unroll
    for (int i = 0; i < (S * TILE) / THREADS; ++i) {  // 4 entries/thread
      int idx = t + THREADS * i;
      int s = idx >> 6;         // idx / TILE
      int jj = idx & (TILE - 1);
      int n = s * sliceLen + k * TILE + jj;
      float qx = ref[n * 3 + 0], qy = ref[n * 3 + 1], qz = ref[n * 3 + 2];
      lds[s * LSTRIDE + jj] =
          (float4_t){qx, qy, qz, qx * qx + qy * qy + qz * qz};
    }
    __syncthreads();
    const float4_t* tp = lds + g * LSTRIDE;  // uniform per 16-lane group
#pragma unroll 2
    for (int j = 0; j < TILE; j += 4) {
      float4_t q0 = tp[j + 0];  // broadcast reads, disjoint banks per wave
      float4_t q1 = tp[j + 1];
      float4_t q2 = tp[j + 2];
      float4_t q3 = tp[j + 3];
      float2_t q0xy = __builtin_shufflevector(q0, q0, 0, 1);
      float2_t q0zw = __builtin_shufflevector(q0, q0, 2, 3);
      float2_t q1xy = __builtin_shufflevector(q1, q1, 0, 1);
      float2_t q1zw = __builtin_shufflevector(q1, q1, 2, 3);
      float2_t q2xy = __builtin_shufflevector(q2, q2, 0, 1);
      float2_t q2zw = __builtin_shufflevector(q2, q2, 2, 3);
      float2_t q3xy = __builtin_shufflevector(q3, q3, 0, 1);
      float2_t q3zw = __builtin_shufflevector(q3, q3, 2, 3);
#pragma unroll
      for (int i = 0; i < P / 2; ++i) {
        // d = ax*qx + ay*qy + az*qz + qw, two points per packed chain
        float2_t d0 = pk_fma_bl(a2x[i], q0xy,
                        pk_fma_bh(a2y[i], q0xy, pk_fma_bl_bh(a2z[i], q0zw)));
        float2_t d1 = pk_fma_bl(a2x[i], q1xy,
                        pk_fma_bh(a2y[i], q1xy, pk_fma_bl_bh(a2z[i], q1zw)));
        float2_t d2 = pk_fma_bl(a2x[i], q2xy,
                        pk_fma_bh(a2y[i], q2xy, pk_fma_bl_bh(a2z[i], q2zw)));
        float2_t d3 = pk_fma_bl(a2x[i], q3xy,
                        pk_fma_bh(a2y[i], q3xy, pk_fma_bl_bh(a2z[i], q3zw)));
        mlo[i] = fminf(fminf(mlo[i], d0.x), d1.x);  // v_min3
        mlo[i] = fminf(fminf(mlo[i], d2.x), d3.x);
        mhi[i] = fminf(fminf(mhi[i], d0.y), d1.y);
        mhi[i] = fminf(fminf(mhi[i], d2.y), d3.y);
      }
    }
  }

  // Combine the S slice-mins per point, then sum the G point-mins.
  __syncthreads();
  float* lmin = (float*)lds;          // [S][G] floats (16 KB, overlays staging)
  float* lcm = (float*)lds + S * G;   // [G] floats
#pragma unroll
  for (int i = 0; i < P / 2; ++i) {
    lmin[g * G + (l + 16 * (2 * i))] = mlo[i];
    lmin[g * G + (l + 16 * (2 * i + 1))] = mhi[i];
    if (g == 0) {
      lcm[l + 16 * (2 * i)] = cm[2 * i];
      lcm[l + 16 * (2 * i + 1)] = cm[2 * i + 1];
    }
  }
  __syncthreads();
  float v = 0.f;
  if (t < G) {
    float mn = 3.0e38f;
#pragma unroll
    for (int s = 0; s < S; ++s) mn = fminf(mn, lmin[s * G + t]);
    v = lcm[t] + mn;
  }
  for (int off = 32; off > 0; off >>= 1) v += __shfl_down(v, off, 64);
  __shared__ float ws[THREADS / 64];
  if ((t & 63) == 0) ws[t >> 6] = v;
  __syncthreads();
  if (t == 0) {
    float bsum = 0.f;
#pragma unroll
    for (int w = 0; w < THREADS / 64; ++w) bsum += ws[w];
    atomicAdd(out, bsum * scale);
  }
}

extern "C" void kernel_launch(void* const* d_in, const int* in_sizes, int n_in,
                              void* d_out, int out_size, void* d_ws,
                              size_t ws_size, hipStream_t stream) {
  const float* pred = (const float*)d_in[0];
  const float* target = (const float*)d_in[1];
  float* out = (float*)d_out;
  const int B = 4;
  const int M = in_sizes[0] / (B * 3);  // 8192

  // mean_b[ mean_m(min) + mean_n(min) ] with M==N  ->  sum_all / (B*M)
  float scale = 1.0f / (float)(B * M);

  hipMemsetAsync(out, 0, sizeof(float), stream);  // d_out is poisoned 0xAA
  int blocks = B * 2 * (M / G);                   // 512
  chamfer_min_kernel<<<blocks, THREADS, 0, stream>>>(pred, target, out, M,
                                                     scale);
}